// Round 1
// 434.415 us; speedup vs baseline: 1.1844x; 1.1844x over previous
//
#include <hip/hip_runtime.h>
#include <hip/hip_bf16.h>
#include <cstdint>

#define N_NODE 512
#define N_GRAPH 8
#define EDIM 1024
#define NHEADS 16
#define HD 64
#define GH 128       // n_graph * NHEADS
#define MROWS 4096   // n_node * n_graph

typedef short bf16x8 __attribute__((ext_vector_type(8)));
typedef float f32x4  __attribute__((ext_vector_type(4)));

__device__ __forceinline__ short f2bs(float f) {
    union { __hip_bfloat16 h; short s; } u; u.h = __float2bfloat16(f); return u.s;
}
__device__ __forceinline__ float bs2f(short s) {
    union { unsigned u; float f; } v; v.u = ((unsigned)(unsigned short)s) << 16; return v.f;
}
// tanh(x) = 1 - 2/(exp(2x)+1): v_exp + v_rcp path (~5 instr vs libm ~25)
__device__ __forceinline__ float fast_tanh(float x) {
    const float e = __expf(2.f * x);
    return 1.f - __fdividef(2.f, 1.f + e);
}

// async global->LDS, 16 B/lane. LDS dest = wave-uniform base + lane*16.
__device__ __forceinline__ void direct_lds16(const short* g, short* l) {
    __builtin_amdgcn_global_load_lds(
        (const __attribute__((address_space(1))) unsigned int*)(uintptr_t)g,
        (__attribute__((address_space(3))) unsigned int*)(unsigned)(uintptr_t)l,
        16, 0, 0);
}

// ---------------- fp32 -> bf16 bulk convert (one-time, 8 elems/thread) ------
__global__ __launch_bounds__(256)
void cvt_bf16(const float* __restrict__ in, short* __restrict__ out, int n8)
{
    const int i = blockIdx.x * 256 + threadIdx.x;
    if (i >= n8) return;
    const float4 f0 = *reinterpret_cast<const float4*>(in + (size_t)i * 8);
    const float4 f1 = *reinterpret_cast<const float4*>(in + (size_t)i * 8 + 4);
    bf16x8 h;
    h[0] = f2bs(f0.x); h[1] = f2bs(f0.y); h[2] = f2bs(f0.z); h[3] = f2bs(f0.w);
    h[4] = f2bs(f1.x); h[5] = f2bs(f1.y); h[6] = f2bs(f1.z); h[7] = f2bs(f1.w);
    *reinterpret_cast<bf16x8*>(out + (size_t)i * 8) = h;
}

// ---------------- MFMA GEMM: C = A @ B^T + bias, bf16 inputs ----------------
// A [M,K], B [N,K] row-major bf16 (as short). 128x128 tile, BK=32,
// global_load_lds width-16 staging into linear [128][32] LDS (m97 structure).
// MODE 0: C row-major [M,N] fp32. MODE 1: qkv scatter, q scaled 0.125.
template<int MODE>
__global__ __launch_bounds__(256)
void gemm_bf16(const short* __restrict__ A, const short* __restrict__ B,
               const float* __restrict__ bias, float* __restrict__ Cout,
               __hip_bfloat16* __restrict__ Cq,
               __hip_bfloat16* __restrict__ Ck,
               __hip_bfloat16* __restrict__ Cv,
               int M, int N, int K)
{
    __shared__ short As[128 * 32];
    __shared__ short Bs[128 * 32];

    const int tid  = threadIdx.x;
    const int m0   = blockIdx.y * 128;
    const int n0   = blockIdx.x * 128;
    const int lane = tid & 63;
    const int w    = tid >> 6;
    const int l16  = lane & 15;
    const int quad = lane >> 4;
    const int wm   = w & 1;
    const int wn   = w >> 1;
    const int lrow = lane >> 2;        // 0..15: row within 16-row staging chunk
    const int lcol = (lane & 3) << 3;  // 0/8/16/24 shorts within BK=32

    const short* ga = A + (size_t)(m0 + w * 16 + lrow) * K + lcol;
    const short* gb = B + (size_t)(n0 + w * 16 + lrow) * K + lcol;
    short* lA = &As[w * 512];          // wave w stages rows [w*16, w*16+16)
    short* lB = &Bs[w * 512];

    f32x4 acc[4][4];
    #pragma unroll
    for (int mt = 0; mt < 4; mt++)
        #pragma unroll
        for (int nt = 0; nt < 4; nt++)
            acc[mt][nt] = (f32x4){0.f, 0.f, 0.f, 0.f};

    for (int k0 = 0; k0 < K; k0 += 32) {
        direct_lds16(ga + k0, lA);                       // rows w*16..
        direct_lds16(ga + (size_t)64 * K + k0, lA + 2048); // rows 64+w*16..
        direct_lds16(gb + k0, lB);
        direct_lds16(gb + (size_t)64 * K + k0, lB + 2048);
        __syncthreads();

        bf16x8 af[4], bfr[4];
        #pragma unroll
        for (int mt = 0; mt < 4; mt++)
            af[mt] = *reinterpret_cast<const bf16x8*>(
                &As[(wm * 64 + mt * 16 + l16) * 32 + quad * 8]);
        #pragma unroll
        for (int nt = 0; nt < 4; nt++)
            bfr[nt] = *reinterpret_cast<const bf16x8*>(
                &Bs[(wn * 64 + nt * 16 + l16) * 32 + quad * 8]);
        #pragma unroll
        for (int mt = 0; mt < 4; mt++)
            #pragma unroll
            for (int nt = 0; nt < 4; nt++)
                acc[mt][nt] = __builtin_amdgcn_mfma_f32_16x16x32_bf16(
                    af[mt], bfr[nt], acc[mt][nt], 0, 0, 0);
        __syncthreads();
    }

    // epilogue: C[m = quad*4+reg (+tiles)][n = l16 (+tiles)]
    #pragma unroll
    for (int nt = 0; nt < 4; nt++) {
        const int c = n0 + wn * 64 + nt * 16 + l16;
        const float bv = bias[c];
        #pragma unroll
        for (int mt = 0; mt < 4; mt++) {
            #pragma unroll
            for (int rr = 0; rr < 4; rr++) {
                const int r = m0 + wm * 64 + mt * 16 + quad * 4 + rr;
                const float v = acc[mt][nt][rr] + bv;
                if (MODE == 0) {
                    Cout[(size_t)r * N + c] = v;
                } else {
                    const int qsel = c >> 10;          // 0=q 1=k 2=v
                    const int e = c & 1023;
                    const int head = e >> 6;
                    const int d = e & 63;
                    const int node = r >> 3;
                    const int graph = r & 7;
                    const int b = graph * NHEADS + head;
                    const size_t idx = ((size_t)b * N_NODE + node) * HD + d;
                    if (qsel == 0)      Cq[idx] = __float2bfloat16(v * 0.125f);
                    else if (qsel == 1) Ck[idx] = __float2bfloat16(v);
                    else                Cv[idx] = __float2bfloat16(v);
                }
            }
        }
    }
}

// ---------------- V transpose: [GH][512][64] -> [GH][64][512] ----------------
__global__ __launch_bounds__(256)
void transpose_v(const __hip_bfloat16* __restrict__ V,
                 __hip_bfloat16* __restrict__ Vt)
{
    __shared__ short T[64][80];
    const int b = blockIdx.y;
    const int jt = blockIdx.x;    // 8 tiles of 64 j
    const int t = threadIdx.x;

    #pragma unroll
    for (int it = 0; it < 2; it++) {
        const int idx = t + it * 256;          // 0..511
        const int j_loc = idx >> 3;
        const int ch = idx & 7;
        bf16x8 v = *reinterpret_cast<const bf16x8*>(
            V + ((size_t)b * N_NODE + jt * 64 + j_loc) * HD + ch * 8);
        *reinterpret_cast<bf16x8*>(&T[j_loc][ch * 8]) = v;
    }
    __syncthreads();
    #pragma unroll
    for (int it = 0; it < 2; it++) {
        const int idx = t + it * 256;
        const int d_loc = idx >> 3;
        const int ch = idx & 7;
        bf16x8 o;
        #pragma unroll
        for (int x = 0; x < 8; x++) o[x] = T[ch * 8 + x][d_loc];
        *reinterpret_cast<bf16x8*>(
            Vt + ((size_t)b * HD + d_loc) * N_NODE + jt * 64 + ch * 8) = o;
    }
}

// ---------------- MFMA attention: 16-row blocks, ~50 KB LDS ------------------
// Phase 1: S = QK^T + bias (fp32 LDS) with fused per-(row,wave) max partials.
// Phase 2: single pass e = exp(S-m) -> Pb bf16, row-sum -> rrs (1/sum deferred).
// Phase 3: Pb *= fast_tanh(gaw)  (gaw reads stay float4-coalesced, 1KB/wave).
// Phase 4: O = (P' V) * rrs via MFMA, P read as aligned bf16x8 (no cvt).
#define SSF 517   // S row stride (floats): 517%32==5 -> ~2-way banks, scalar use only
#define SPB 520   // Pb row stride (shorts): 1040 B, 16B-aligned rows for b128

__global__ __launch_bounds__(256)
void attn_mfma(const __hip_bfloat16* __restrict__ Qh,
               const __hip_bfloat16* __restrict__ Kh,
               const __hip_bfloat16* __restrict__ Vt,
               const float* __restrict__ bias,
               const float* __restrict__ gaw,
               __hip_bfloat16* __restrict__ A2)
{
    __shared__ __align__(16) float S[16][SSF];     // 33,088 B
    __shared__ __align__(16) short Pb[16][SPB];    // 16,640 B
    __shared__ __align__(16) float mpart[16][4];
    __shared__ float rrs[16];

    const int b    = blockIdx.y;
    const int i0   = blockIdx.x * 16;
    const int tid  = threadIdx.x;
    const int lane = tid & 63;
    const int w    = tid >> 6;
    const int quad = lane >> 4;
    const int l16  = lane & 15;

    // ---- phase 1: S = Q K^T + bias, fused row-max partials ----
    {
        const __hip_bfloat16* Qb =
            Qh + ((size_t)b * N_NODE + i0 + l16) * HD + quad * 8;
        const bf16x8 qa0 = *reinterpret_cast<const bf16x8*>(Qb);
        const bf16x8 qa1 = *reinterpret_cast<const bf16x8*>(Qb + 32);
        const int row_l = quad * 4;
        const float* bp0 = bias + ((size_t)b * N_NODE + i0 + row_l) * N_NODE + l16;
        float mxr[4] = {-1e30f, -1e30f, -1e30f, -1e30f};

        #pragma unroll 2
        for (int jt = w; jt < 32; jt += 4) {
            const __hip_bfloat16* Kb =
                Kh + ((size_t)b * N_NODE + jt * 16 + l16) * HD + quad * 8;
            const bf16x8 k0 = *reinterpret_cast<const bf16x8*>(Kb);
            const bf16x8 k1 = *reinterpret_cast<const bf16x8*>(Kb + 32);
            f32x4 acc = {0.f, 0.f, 0.f, 0.f};
            acc = __builtin_amdgcn_mfma_f32_16x16x32_bf16(qa0, k0, acc, 0, 0, 0);
            acc = __builtin_amdgcn_mfma_f32_16x16x32_bf16(qa1, k1, acc, 0, 0, 0);
            const float* bp = bp0 + jt * 16;
            #pragma unroll
            for (int r = 0; r < 4; r++) {
                const float v = acc[r] + bp[(size_t)r * N_NODE];
                S[row_l + r][jt * 16 + l16] = v;
                mxr[r] = fmaxf(mxr[r], v);
            }
        }
        #pragma unroll
        for (int r = 0; r < 4; r++) {
            float m = mxr[r];
            m = fmaxf(m, __shfl_xor(m, 1));
            m = fmaxf(m, __shfl_xor(m, 2));
            m = fmaxf(m, __shfl_xor(m, 4));
            m = fmaxf(m, __shfl_xor(m, 8));
            if (l16 == 0) mpart[row_l + r][w] = m;
        }
    }
    __syncthreads();

    // ---- phase 2: e = exp(S - m) -> Pb (bf16), rowsum -> rrs ----
    {
        const int r   = tid >> 4;
        const int c16 = tid & 15;
        const float4 mp = *reinterpret_cast<const float4*>(mpart[r]);
        const float m = fmaxf(fmaxf(mp.x, mp.y), fmaxf(mp.z, mp.w));
        float sum = 0.f;
        #pragma unroll 4
        for (int jj = 0; jj < 32; jj++) {
            const float e = __expf(S[r][c16 + 16 * jj] - m);
            sum += e;
            Pb[r][c16 + 16 * jj] = f2bs(e);
        }
        sum += __shfl_xor(sum, 1);
        sum += __shfl_xor(sum, 2);
        sum += __shfl_xor(sum, 4);
        sum += __shfl_xor(sum, 8);
        if (c16 == 0) rrs[r] = 1.f / sum;
    }
    __syncthreads();

    // ---- phase 3: Pb *= tanh(gaw)  (gaw float4, 1KB/wave coalesced) ----
    {
        const float* gb = gaw + ((size_t)b * N_NODE + i0) * N_NODE;
        #pragma unroll 2
        for (int it = 0; it < 8; it++) {
            const int idx = tid * 4 + it * 1024;
            const int r = idx >> 9;
            const int j = idx & 511;
            const float4 g = *reinterpret_cast<const float4*>(gb + idx);
            const short4 e4 = *reinterpret_cast<const short4*>(&Pb[r][j]);
            short4 o4;
            o4.x = f2bs(fast_tanh(g.x) * bs2f(e4.x));
            o4.y = f2bs(fast_tanh(g.y) * bs2f(e4.y));
            o4.z = f2bs(fast_tanh(g.z) * bs2f(e4.z));
            o4.w = f2bs(fast_tanh(g.w) * bs2f(e4.w));
            *reinterpret_cast<short4*>(&Pb[r][j]) = o4;
        }
    }
    __syncthreads();

    // ---- phase 4: O = (P' V) * rrs ----
    {
        const __hip_bfloat16* Vb =
            Vt + ((size_t)b * HD + w * 16 + l16) * N_NODE + quad * 8;
        f32x4 acc = {0.f, 0.f, 0.f, 0.f};
        #pragma unroll 4
        for (int j32 = 0; j32 < 16; j32++) {
            const bf16x8 af =
                *reinterpret_cast<const bf16x8*>(&Pb[l16][j32 * 32 + quad * 8]);
            const bf16x8 bfr = *reinterpret_cast<const bf16x8*>(Vb + j32 * 32);
            acc = __builtin_amdgcn_mfma_f32_16x16x32_bf16(af, bfr, acc, 0, 0, 0);
        }
        const int node0 = i0 + quad * 4;
        __hip_bfloat16* op = A2 + (size_t)node0 * (N_GRAPH * EDIM)
                           + (b >> 4) * EDIM + (b & 15) * HD + w * 16 + l16;
        #pragma unroll
        for (int r = 0; r < 4; r++)
            op[(size_t)r * (N_GRAPH * EDIM)] =
                __float2bfloat16(acc[r] * rrs[quad * 4 + r]);
    }
}

extern "C" void kernel_launch(void* const* d_in, const int* in_sizes, int n_in,
                              void* d_out, int out_size, void* d_ws, size_t ws_size,
                              hipStream_t stream) {
    const float* query     = (const float*)d_in[0];
    const float* attn_bias = (const float*)d_in[1];
    const float* gaw       = (const float*)d_in[2];
    const float* in_w      = (const float*)d_in[3];
    const float* in_b      = (const float*)d_in[4];
    const float* out_w     = (const float*)d_in[5];
    const float* out_b     = (const float*)d_in[6];
    float* out = (float*)d_out;

    // workspace layout (shorts). Requires ws_size >= 40 MB.
    short* wsp = (short*)d_ws;
    const size_t hsz = (size_t)GH * N_NODE * HD;      // 4 Mi elems
    short* Q   = wsp;
    short* K   = wsp + hsz;
    short* V   = wsp + 2 * hsz;
    short* Vt  = wsp + 3 * hsz;
    short* A2  = V;                       // V dead after transpose
    short* qb  = Vt;                      // qb dead before transpose writes Vt
    short* wbi = wsp + 4 * hsz;           // in_w bf16  (3 Mi)
    short* wbo = wbi + (size_t)3 * EDIM * EDIM;  // out_w bf16 (1 Mi)

    // 0) one-time bf16 conversions (numerically identical to per-tile cvt)
    cvt_bf16<<<dim3(MROWS * EDIM / 2048), 256, 0, stream>>>(query, qb, MROWS * EDIM / 8);
    cvt_bf16<<<dim3(3 * EDIM * EDIM / 2048), 256, 0, stream>>>(in_w, wbi, 3 * EDIM * EDIM / 8);
    cvt_bf16<<<dim3(EDIM * EDIM / 2048), 256, 0, stream>>>(out_w, wbo, EDIM * EDIM / 8);

    // 1) fused QKV projection + head-layout scatter
    gemm_bf16<1><<<dim3(24, 32), 256, 0, stream>>>(
        qb, wbi, in_b, nullptr,
        (__hip_bfloat16*)Q, (__hip_bfloat16*)K, (__hip_bfloat16*)V,
        MROWS, 3 * EDIM, EDIM);

    // 2) V -> Vt (overwrites qb, which is dead)
    transpose_v<<<dim3(8, GH), 256, 0, stream>>>(
        (const __hip_bfloat16*)V, (__hip_bfloat16*)Vt);

    // 3) MFMA attention (16-row blocks)
    attn_mfma<<<dim3(N_NODE / 16, GH), 256, 0, stream>>>(
        (const __hip_bfloat16*)Q, (const __hip_bfloat16*)K,
        (const __hip_bfloat16*)Vt, attn_bias, gaw, (__hip_bfloat16*)A2);

    // 4) output projection
    gemm_bf16<0><<<dim3(8, 32), 256, 0, stream>>>(
        (const short*)A2, wbo, out_b, out,
        nullptr, nullptr, nullptr, MROWS, EDIM, EDIM);
}

// Round 2
// 426.708 us; speedup vs baseline: 1.2058x; 1.0181x over previous
//
#include <hip/hip_runtime.h>
#include <hip/hip_bf16.h>
#include <cstdint>

#define N_NODE 512
#define N_GRAPH 8
#define EDIM 1024
#define NHEADS 16
#define HD 64
#define GH 128       // n_graph * NHEADS
#define MROWS 4096   // n_node * n_graph

typedef short bf16x8 __attribute__((ext_vector_type(8)));
typedef float f32x4  __attribute__((ext_vector_type(4)));

__device__ __forceinline__ short f2bs(float f) {
    union { __hip_bfloat16 h; short s; } u; u.h = __float2bfloat16(f); return u.s;
}
__device__ __forceinline__ float bs2f(short s) {
    union { unsigned u; float f; } v; v.u = ((unsigned)(unsigned short)s) << 16; return v.f;
}
// tanh(x) = 1 - 2/(exp(2x)+1): v_exp + v_rcp path (~5 instr vs libm ~25)
__device__ __forceinline__ float fast_tanh(float x) {
    const float e = __expf(2.f * x);
    return 1.f - __fdividef(2.f, 1.f + e);
}

// async global->LDS, 16 B/lane. LDS dest = wave-uniform base + lane*16.
__device__ __forceinline__ void direct_lds16(const short* g, short* l) {
    __builtin_amdgcn_global_load_lds(
        (const __attribute__((address_space(1))) unsigned int*)(uintptr_t)g,
        (__attribute__((address_space(3))) unsigned int*)(unsigned)(uintptr_t)l,
        16, 0, 0);
}

// ---------------- fp32 -> bf16 bulk convert (one-time, 8 elems/thread) ------
__global__ __launch_bounds__(256)
void cvt_bf16(const float* __restrict__ in, short* __restrict__ out, int n8)
{
    const int i = blockIdx.x * 256 + threadIdx.x;
    if (i >= n8) return;
    const float4 f0 = *reinterpret_cast<const float4*>(in + (size_t)i * 8);
    const float4 f1 = *reinterpret_cast<const float4*>(in + (size_t)i * 8 + 4);
    bf16x8 h;
    h[0] = f2bs(f0.x); h[1] = f2bs(f0.y); h[2] = f2bs(f0.z); h[3] = f2bs(f0.w);
    h[4] = f2bs(f1.x); h[5] = f2bs(f1.y); h[6] = f2bs(f1.z); h[7] = f2bs(f1.w);
    *reinterpret_cast<bf16x8*>(out + (size_t)i * 8) = h;
}

// ---------------- MFMA GEMM: C = A @ B^T + bias, bf16 inputs ----------------
// A [M,K], B [N,K] row-major bf16 (as short). 128x128 tile, BK=32,
// global_load_lds width-16 staging into linear [128][32] LDS (m97 structure).
// XCD-aware bijective block swizzle (grid count divisible by 8).
// MODE 0: C row-major [M,N] fp32. MODE 1: qkv scatter, q scaled 0.125.
template<int MODE>
__global__ __launch_bounds__(256)
void gemm_bf16(const short* __restrict__ A, const short* __restrict__ B,
               const float* __restrict__ bias, float* __restrict__ Cout,
               __hip_bfloat16* __restrict__ Cq,
               __hip_bfloat16* __restrict__ Ck,
               __hip_bfloat16* __restrict__ Cv,
               int M, int N, int K)
{
    __shared__ short As[128 * 32];
    __shared__ short Bs[128 * 32];

    // XCD swizzle: hw dispatches flat ids round-robin over 8 XCDs; remap so
    // each XCD owns a contiguous chunk of logical tiles (A-panel L2 reuse).
    const int nwg  = gridDim.x * gridDim.y;
    const int flat = blockIdx.y * gridDim.x + blockIdx.x;
    const int q8   = nwg >> 3;                    // both grids divisible by 8
    const int swz  = (flat & 7) * q8 + (flat >> 3);
    const int bx   = swz % gridDim.x;
    const int by   = swz / gridDim.x;

    const int tid  = threadIdx.x;
    const int m0   = by * 128;
    const int n0   = bx * 128;
    const int lane = tid & 63;
    const int w    = tid >> 6;
    const int l16  = lane & 15;
    const int quad = lane >> 4;
    const int wm   = w & 1;
    const int wn   = w >> 1;
    const int lrow = lane >> 2;        // 0..15: row within 16-row staging chunk
    const int lcol = (lane & 3) << 3;  // 0/8/16/24 shorts within BK=32

    const short* ga = A + (size_t)(m0 + w * 16 + lrow) * K + lcol;
    const short* gb = B + (size_t)(n0 + w * 16 + lrow) * K + lcol;
    short* lA = &As[w * 512];          // wave w stages rows [w*16, w*16+16)
    short* lB = &Bs[w * 512];

    f32x4 acc[4][4];
    #pragma unroll
    for (int mt = 0; mt < 4; mt++)
        #pragma unroll
        for (int nt = 0; nt < 4; nt++)
            acc[mt][nt] = (f32x4){0.f, 0.f, 0.f, 0.f};

    for (int k0 = 0; k0 < K; k0 += 32) {
        direct_lds16(ga + k0, lA);                         // rows w*16..
        direct_lds16(ga + (size_t)64 * K + k0, lA + 2048); // rows 64+w*16..
        direct_lds16(gb + k0, lB);
        direct_lds16(gb + (size_t)64 * K + k0, lB + 2048);
        __syncthreads();

        bf16x8 af[4], bfr[4];
        #pragma unroll
        for (int mt = 0; mt < 4; mt++)
            af[mt] = *reinterpret_cast<const bf16x8*>(
                &As[(wm * 64 + mt * 16 + l16) * 32 + quad * 8]);
        #pragma unroll
        for (int nt = 0; nt < 4; nt++)
            bfr[nt] = *reinterpret_cast<const bf16x8*>(
                &Bs[(wn * 64 + nt * 16 + l16) * 32 + quad * 8]);
        #pragma unroll
        for (int mt = 0; mt < 4; mt++)
            #pragma unroll
            for (int nt = 0; nt < 4; nt++)
                acc[mt][nt] = __builtin_amdgcn_mfma_f32_16x16x32_bf16(
                    af[mt], bfr[nt], acc[mt][nt], 0, 0, 0);
        __syncthreads();
    }

    // epilogue: C[m = quad*4+reg (+tiles)][n = l16 (+tiles)]
    #pragma unroll
    for (int nt = 0; nt < 4; nt++) {
        const int c = n0 + wn * 64 + nt * 16 + l16;
        const float bv = bias[c];
        #pragma unroll
        for (int mt = 0; mt < 4; mt++) {
            #pragma unroll
            for (int rr = 0; rr < 4; rr++) {
                const int r = m0 + wm * 64 + mt * 16 + quad * 4 + rr;
                const float v = acc[mt][nt][rr] + bv;
                if (MODE == 0) {
                    Cout[(size_t)r * N + c] = v;
                } else {
                    const int qsel = c >> 10;          // 0=q 1=k 2=v
                    const int e = c & 1023;
                    const int head = e >> 6;
                    const int d = e & 63;
                    const int node = r >> 3;
                    const int graph = r & 7;
                    const int b = graph * NHEADS + head;
                    const size_t idx = ((size_t)b * N_NODE + node) * HD + d;
                    if (qsel == 0)      Cq[idx] = __float2bfloat16(v * 0.125f);
                    else if (qsel == 1) Ck[idx] = __float2bfloat16(v);
                    else                Cv[idx] = __float2bfloat16(v);
                }
            }
        }
    }
}

// ---------------- V transpose: [GH][512][64] -> [GH][64][512] ----------------
__global__ __launch_bounds__(256)
void transpose_v(const __hip_bfloat16* __restrict__ V,
                 __hip_bfloat16* __restrict__ Vt)
{
    __shared__ short T[64][80];
    const int b = blockIdx.y;
    const int jt = blockIdx.x;    // 8 tiles of 64 j
    const int t = threadIdx.x;

    #pragma unroll
    for (int it = 0; it < 2; it++) {
        const int idx = t + it * 256;          // 0..511
        const int j_loc = idx >> 3;
        const int ch = idx & 7;
        bf16x8 v = *reinterpret_cast<const bf16x8*>(
            V + ((size_t)b * N_NODE + jt * 64 + j_loc) * HD + ch * 8);
        *reinterpret_cast<bf16x8*>(&T[j_loc][ch * 8]) = v;
    }
    __syncthreads();
    #pragma unroll
    for (int it = 0; it < 2; it++) {
        const int idx = t + it * 256;
        const int d_loc = idx >> 3;
        const int ch = idx & 7;
        bf16x8 o;
        #pragma unroll
        for (int x = 0; x < 8; x++) o[x] = T[ch * 8 + x][d_loc];
        *reinterpret_cast<bf16x8*>(
            Vt + ((size_t)b * HD + d_loc) * N_NODE + jt * 64 + ch * 8) = o;
    }
}

// ---------------- MFMA attention: S fully in registers, ~17 KB LDS ----------
// Lane (quad,l16) of wave w owns S rows quad*4..+3, cols {w+4t}*16+l16, t=0..7
// (the MFMA C-layout). Phase 1: QK^T + bias into sreg, fused row-max partials.
// Phase 2: e = exp(S-m); p = tanh(gaw)*e; Pb (bf16, XOR-swizzled) written ONCE;
//          per-wave row-sum partials (1/sum deferred to epilogue).
// Phase 3: O = (P V) * rrs via MFMA; Pb read as b128, conflict-free via swizzle.
#define PBS 512   // Pb row stride in shorts (1024 B); bank-spread via XOR swizzle

__global__ __launch_bounds__(256, 4)
void attn_mfma(const __hip_bfloat16* __restrict__ Qh,
               const __hip_bfloat16* __restrict__ Kh,
               const __hip_bfloat16* __restrict__ Vt,
               const float* __restrict__ bias,
               const float* __restrict__ gaw,
               __hip_bfloat16* __restrict__ A2)
{
    __shared__ __align__(16) short Pb[16 * PBS];   // 16,384 B
    __shared__ __align__(16) float mpart[16][4];
    __shared__ __align__(16) float spart[16][4];

    const int b    = blockIdx.y;
    const int i0   = blockIdx.x * 16;
    const int tid  = threadIdx.x;
    const int lane = tid & 63;
    const int w    = tid >> 6;
    const int quad = lane >> 4;
    const int l16  = lane & 15;
    const int row_l = quad * 4;

    f32x4 sreg[8];

    // ---- phase 1: S = Q K^T + bias in registers, fused row-max partials ----
    {
        const __hip_bfloat16* Qb =
            Qh + ((size_t)b * N_NODE + i0 + l16) * HD + quad * 8;
        const bf16x8 qa0 = *reinterpret_cast<const bf16x8*>(Qb);
        const bf16x8 qa1 = *reinterpret_cast<const bf16x8*>(Qb + 32);
        const float* bp0 = bias + ((size_t)b * N_NODE + i0 + row_l) * N_NODE + l16;
        float mx[4] = {-1e30f, -1e30f, -1e30f, -1e30f};

        #pragma unroll
        for (int t = 0; t < 8; t++) {
            const int jt = w + 4 * t;
            const __hip_bfloat16* Kb =
                Kh + ((size_t)b * N_NODE + jt * 16 + l16) * HD + quad * 8;
            const bf16x8 k0 = *reinterpret_cast<const bf16x8*>(Kb);
            const bf16x8 k1 = *reinterpret_cast<const bf16x8*>(Kb + 32);
            f32x4 acc = {0.f, 0.f, 0.f, 0.f};
            acc = __builtin_amdgcn_mfma_f32_16x16x32_bf16(qa0, k0, acc, 0, 0, 0);
            acc = __builtin_amdgcn_mfma_f32_16x16x32_bf16(qa1, k1, acc, 0, 0, 0);
            const float* bp = bp0 + jt * 16;
            #pragma unroll
            for (int r = 0; r < 4; r++) {
                acc[r] += bp[(size_t)r * N_NODE];
                mx[r] = fmaxf(mx[r], acc[r]);
            }
            sreg[t] = acc;
        }
        #pragma unroll
        for (int r = 0; r < 4; r++) {
            float m = mx[r];
            m = fmaxf(m, __shfl_xor(m, 1));
            m = fmaxf(m, __shfl_xor(m, 2));
            m = fmaxf(m, __shfl_xor(m, 4));
            m = fmaxf(m, __shfl_xor(m, 8));
            if (l16 == 0) mpart[row_l + r][w] = m;
        }
    }
    __syncthreads();

    // ---- phase 2: p = tanh(gaw) * exp(S - m) -> Pb (once); row-sum partials --
    {
        float mrow[4];
        #pragma unroll
        for (int r = 0; r < 4; r++) {
            const float4 mp = *reinterpret_cast<const float4*>(mpart[row_l + r]);
            mrow[r] = fmaxf(fmaxf(mp.x, mp.y), fmaxf(mp.z, mp.w));
        }
        float sum[4] = {0.f, 0.f, 0.f, 0.f};
        const float* gp0 = gaw + ((size_t)b * N_NODE + i0 + row_l) * N_NODE + l16;

        #pragma unroll
        for (int t = 0; t < 8; t++) {
            const int jt = w + 4 * t;
            const int colb = (jt * 16 + l16) * 2;       // byte offset of col
            const float* gp = gp0 + jt * 16;
            #pragma unroll
            for (int r = 0; r < 4; r++) {
                const float e = __expf(sreg[t][r] - mrow[r]);
                sum[r] += e;
                const float g = gp[(size_t)r * N_NODE];
                const float p = fast_tanh(g) * e;
                const int row = row_l + r;
                const int byte = row * (PBS * 2) + (colb ^ ((row & 7) << 4));
                *reinterpret_cast<short*>(reinterpret_cast<char*>(Pb) + byte) = f2bs(p);
            }
        }
        #pragma unroll
        for (int r = 0; r < 4; r++) {
            float s = sum[r];
            s += __shfl_xor(s, 1);
            s += __shfl_xor(s, 2);
            s += __shfl_xor(s, 4);
            s += __shfl_xor(s, 8);
            if (l16 == 0) spart[row_l + r][w] = s;
        }
    }
    __syncthreads();

    // ---- phase 3: O = (P V) * rrs ----
    {
        const __hip_bfloat16* Vb =
            Vt + ((size_t)b * HD + w * 16 + l16) * N_NODE + quad * 8;
        f32x4 acc = {0.f, 0.f, 0.f, 0.f};
        #pragma unroll
        for (int j32 = 0; j32 < 16; j32++) {
            const int byte = l16 * (PBS * 2)
                           + ((j32 * 64 + quad * 16) ^ ((l16 & 7) << 4));
            const bf16x8 af = *reinterpret_cast<const bf16x8*>(
                reinterpret_cast<const char*>(Pb) + byte);
            const bf16x8 bfr = *reinterpret_cast<const bf16x8*>(Vb + j32 * 32);
            acc = __builtin_amdgcn_mfma_f32_16x16x32_bf16(af, bfr, acc, 0, 0, 0);
        }
        const int node0 = i0 + quad * 4;
        __hip_bfloat16* op = A2 + (size_t)node0 * (N_GRAPH * EDIM)
                           + (b >> 4) * EDIM + (b & 15) * HD + w * 16 + l16;
        #pragma unroll
        for (int r = 0; r < 4; r++) {
            const float4 sp = *reinterpret_cast<const float4*>(spart[quad * 4 + r]);
            const float rs = 1.f / (sp.x + sp.y + sp.z + sp.w);
            op[(size_t)r * (N_GRAPH * EDIM)] = __float2bfloat16(acc[r] * rs);
        }
    }
}

extern "C" void kernel_launch(void* const* d_in, const int* in_sizes, int n_in,
                              void* d_out, int out_size, void* d_ws, size_t ws_size,
                              hipStream_t stream) {
    const float* query     = (const float*)d_in[0];
    const float* attn_bias = (const float*)d_in[1];
    const float* gaw       = (const float*)d_in[2];
    const float* in_w      = (const float*)d_in[3];
    const float* in_b      = (const float*)d_in[4];
    const float* out_w     = (const float*)d_in[5];
    const float* out_b     = (const float*)d_in[6];
    float* out = (float*)d_out;

    // workspace layout (shorts). Requires ws_size >= 40 MB.
    short* wsp = (short*)d_ws;
    const size_t hsz = (size_t)GH * N_NODE * HD;      // 4 Mi elems
    short* Q   = wsp;
    short* K   = wsp + hsz;
    short* V   = wsp + 2 * hsz;
    short* Vt  = wsp + 3 * hsz;
    short* A2  = V;                       // V dead after transpose
    short* qb  = Vt;                      // qb dead before transpose writes Vt
    short* wbi = wsp + 4 * hsz;           // in_w bf16  (3 Mi)
    short* wbo = wbi + (size_t)3 * EDIM * EDIM;  // out_w bf16 (1 Mi)

    // 0) one-time bf16 conversions (numerically identical to per-tile cvt)
    cvt_bf16<<<dim3(MROWS * EDIM / 2048), 256, 0, stream>>>(query, qb, MROWS * EDIM / 8);
    cvt_bf16<<<dim3(3 * EDIM * EDIM / 2048), 256, 0, stream>>>(in_w, wbi, 3 * EDIM * EDIM / 8);
    cvt_bf16<<<dim3(EDIM * EDIM / 2048), 256, 0, stream>>>(out_w, wbo, EDIM * EDIM / 8);

    // 1) fused QKV projection + head-layout scatter
    gemm_bf16<1><<<dim3(24, 32), 256, 0, stream>>>(
        qb, wbi, in_b, nullptr,
        (__hip_bfloat16*)Q, (__hip_bfloat16*)K, (__hip_bfloat16*)V,
        MROWS, 3 * EDIM, EDIM);

    // 2) V -> Vt (overwrites qb, which is dead)
    transpose_v<<<dim3(8, GH), 256, 0, stream>>>(
        (const __hip_bfloat16*)V, (__hip_bfloat16*)Vt);

    // 3) MFMA attention (16-row blocks, register-resident S)
    attn_mfma<<<dim3(N_NODE / 16, GH), 256, 0, stream>>>(
        (const __hip_bfloat16*)Q, (const __hip_bfloat16*)K,
        (const __hip_bfloat16*)Vt, attn_bias, gaw, (__hip_bfloat16*)A2);

    // 4) output projection
    gemm_bf16<0><<<dim3(8, 32), 256, 0, stream>>>(
        (const short*)A2, wbo, out_b, out,
        nullptr, nullptr, nullptr, MROWS, EDIM, EDIM);
}

// Round 3
// 411.384 us; speedup vs baseline: 1.2507x; 1.0373x over previous
//
#include <hip/hip_runtime.h>
#include <hip/hip_bf16.h>
#include <cstdint>

#define N_NODE 512
#define N_GRAPH 8
#define EDIM 1024
#define NHEADS 16
#define HD 64
#define GH 128       // n_graph * NHEADS
#define MROWS 4096   // n_node * n_graph

typedef short bf16x8 __attribute__((ext_vector_type(8)));
typedef float f32x4  __attribute__((ext_vector_type(4)));

__device__ __forceinline__ short f2bs(float f) {
    union { __hip_bfloat16 h; short s; } u; u.h = __float2bfloat16(f); return u.s;
}
// tanh(x) = 1 - 2/(exp(2x)+1): v_exp + v_rcp path (~5 instr vs libm ~25)
__device__ __forceinline__ float fast_tanh(float x) {
    const float e = __expf(2.f * x);
    return 1.f - __fdividef(2.f, 1.f + e);
}

// async global->LDS, 16 B/lane. LDS dest = wave-uniform base + lane*16.
__device__ __forceinline__ void direct_lds16(const short* g, short* l) {
    __builtin_amdgcn_global_load_lds(
        (const __attribute__((address_space(1))) unsigned int*)(uintptr_t)g,
        (__attribute__((address_space(3))) unsigned int*)(unsigned)(uintptr_t)l,
        16, 0, 0);
}

// ---------------- fp32 -> bf16 bulk convert (one-time, 8 elems/thread) ------
__global__ __launch_bounds__(256)
void cvt_bf16(const float* __restrict__ in, short* __restrict__ out, int n8)
{
    const int i = blockIdx.x * 256 + threadIdx.x;
    if (i >= n8) return;
    const float4 f0 = *reinterpret_cast<const float4*>(in + (size_t)i * 8);
    const float4 f1 = *reinterpret_cast<const float4*>(in + (size_t)i * 8 + 4);
    bf16x8 h;
    h[0] = f2bs(f0.x); h[1] = f2bs(f0.y); h[2] = f2bs(f0.z); h[3] = f2bs(f0.w);
    h[4] = f2bs(f1.x); h[5] = f2bs(f1.y); h[6] = f2bs(f1.z); h[7] = f2bs(f1.w);
    *reinterpret_cast<bf16x8*>(out + (size_t)i * 8) = h;
}

// ---------------- MFMA GEMM: C = A @ B^T + bias, bf16 inputs ----------------
// A [M,K], B [N,K] row-major bf16. 128xBN tile, BK=32. 3-buffer LDS pipeline:
// per K-step {STAGE next -> vmcnt(counted) -> s_barrier -> ds_read+MFMA}.
// Counted vmcnt never drains the just-issued loads (T3+T4). XCD-swizzled grid.
// MODE 0 (BN=64): C row-major fp32. MODE 1 (BN=128): qkv scatter, q*0.125.
template<int MODE, int BN>
__global__ __launch_bounds__(256)
void gemm_bf16(const short* __restrict__ A, const short* __restrict__ B,
               const float* __restrict__ bias, float* __restrict__ Cout,
               __hip_bfloat16* __restrict__ Cq,
               __hip_bfloat16* __restrict__ Ck,
               __hip_bfloat16* __restrict__ Cv,
               int M, int N, int K)
{
    __shared__ short As[3][128 * 32];
    __shared__ short Bs[3][BN * 32];

    // XCD swizzle: contiguous logical-tile chunk per XCD (both grids % 8 == 0)
    const int nwg  = gridDim.x * gridDim.y;
    const int flat = blockIdx.y * gridDim.x + blockIdx.x;
    const int q8   = nwg >> 3;
    const int swz  = (flat & 7) * q8 + (flat >> 3);
    const int bx   = swz % gridDim.x;
    const int by   = swz / gridDim.x;

    const int tid  = threadIdx.x;
    const int m0   = by * 128;
    const int n0   = bx * BN;
    const int lane = tid & 63;
    const int w    = tid >> 6;
    const int l16  = lane & 15;
    const int quad = lane >> 4;
    const int wm   = w & 1;
    const int wn   = w >> 1;
    const int lrow = lane >> 2;        // 0..15 row within 16-row staging chunk
    const int lcol = (lane & 3) << 3;  // 0/8/16/24 shorts within BK=32

    const short* ga = A + (size_t)(m0 + w * 16 + lrow) * K + lcol;
    const short* gb = B + (size_t)(n0 + w * 16 + lrow) * K + lcol;

    constexpr int NTC = BN / 32;       // col fragments per wave (4 or 2)

    f32x4 acc[4][NTC];
    #pragma unroll
    for (int mt = 0; mt < 4; mt++)
        #pragma unroll
        for (int nt = 0; nt < NTC; nt++)
            acc[mt][nt] = (f32x4){0.f, 0.f, 0.f, 0.f};

    auto STAGE = [&](int kk, int buf) {
        short* lA = &As[buf][w * 512];
        direct_lds16(ga + kk, lA);
        direct_lds16(ga + (size_t)64 * K + kk, lA + 2048);
        short* lB = &Bs[buf][w * 512];
        direct_lds16(gb + kk, lB);
        if constexpr (BN == 128)
            direct_lds16(gb + (size_t)64 * K + kk, lB + 2048);
    };

    const int NT = K >> 5;             // 32 K-steps
    STAGE(0, 0);
    int cur = 0, nxt = 1;
    for (int t = 0; t < NT; ++t) {
        if (t + 1 < NT) {
            STAGE((t + 1) << 5, nxt);
            if constexpr (BN == 128)
                asm volatile("s_waitcnt vmcnt(4)" ::: "memory");
            else
                asm volatile("s_waitcnt vmcnt(3)" ::: "memory");
        } else {
            asm volatile("s_waitcnt vmcnt(0)" ::: "memory");
        }
        __builtin_amdgcn_s_barrier();
        __builtin_amdgcn_sched_barrier(0);

        bf16x8 af[4], bfr[NTC];
        #pragma unroll
        for (int mt = 0; mt < 4; mt++)
            af[mt] = *reinterpret_cast<const bf16x8*>(
                &As[cur][(wm * 64 + mt * 16 + l16) * 32 + quad * 8]);
        #pragma unroll
        for (int nt = 0; nt < NTC; nt++)
            bfr[nt] = *reinterpret_cast<const bf16x8*>(
                &Bs[cur][(wn * (BN / 2) + nt * 16 + l16) * 32 + quad * 8]);
        #pragma unroll
        for (int mt = 0; mt < 4; mt++)
            #pragma unroll
            for (int nt = 0; nt < NTC; nt++)
                acc[mt][nt] = __builtin_amdgcn_mfma_f32_16x16x32_bf16(
                    af[mt], bfr[nt], acc[mt][nt], 0, 0, 0);

        cur = (cur == 2) ? 0 : cur + 1;
        nxt = (nxt == 2) ? 0 : nxt + 1;
    }

    // epilogue: C[m = quad*4+reg (+tiles)][n = l16 (+tiles)]
    #pragma unroll
    for (int nt = 0; nt < NTC; nt++) {
        const int c = n0 + wn * (BN / 2) + nt * 16 + l16;
        const float bv = bias[c];
        #pragma unroll
        for (int mt = 0; mt < 4; mt++) {
            #pragma unroll
            for (int rr = 0; rr < 4; rr++) {
                const int r = m0 + wm * 64 + mt * 16 + quad * 4 + rr;
                const float v = acc[mt][nt][rr] + bv;
                if (MODE == 0) {
                    Cout[(size_t)r * N + c] = v;
                } else {
                    const int qsel = c >> 10;          // 0=q 1=k 2=v
                    const int e = c & 1023;
                    const int head = e >> 6;
                    const int d = e & 63;
                    const int node = r >> 3;
                    const int graph = r & 7;
                    const int b = graph * NHEADS + head;
                    const size_t idx = ((size_t)b * N_NODE + node) * HD + d;
                    if (qsel == 0)      Cq[idx] = __float2bfloat16(v * 0.125f);
                    else if (qsel == 1) Ck[idx] = __float2bfloat16(v);
                    else                Cv[idx] = __float2bfloat16(v);
                }
            }
        }
    }
}

// ---------------- V transpose: [GH][512][64] -> [GH][64][512] ----------------
__global__ __launch_bounds__(256)
void transpose_v(const __hip_bfloat16* __restrict__ V,
                 __hip_bfloat16* __restrict__ Vt)
{
    __shared__ short T[64][80];
    const int b = blockIdx.y;
    const int jt = blockIdx.x;    // 8 tiles of 64 j
    const int t = threadIdx.x;

    #pragma unroll
    for (int it = 0; it < 2; it++) {
        const int idx = t + it * 256;          // 0..511
        const int j_loc = idx >> 3;
        const int ch = idx & 7;
        bf16x8 v = *reinterpret_cast<const bf16x8*>(
            V + ((size_t)b * N_NODE + jt * 64 + j_loc) * HD + ch * 8);
        *reinterpret_cast<bf16x8*>(&T[j_loc][ch * 8]) = v;
    }
    __syncthreads();
    #pragma unroll
    for (int it = 0; it < 2; it++) {
        const int idx = t + it * 256;
        const int d_loc = idx >> 3;
        const int ch = idx & 7;
        bf16x8 o;
        #pragma unroll
        for (int x = 0; x < 8; x++) o[x] = T[ch * 8 + x][d_loc];
        *reinterpret_cast<bf16x8*>(
            Vt + ((size_t)b * HD + d_loc) * N_NODE + jt * 64 + ch * 8) = o;
    }
}

// ---------------- MFMA attention: swapped QK^T, float4 bias/gaw --------------
// mfma(K,Q) -> lane (quad,l16) holds S[row = i0+l16][col = jt*16+quad*4+r].
// bias/gaw are float4 loads (16 rows x 64B contiguous per wave-instr).
// All K fragments + bias issued up front (high MLP); gaw issued before the
// max-reduce barrier; V issued before the phase-2 barrier (drained there).
// Pb bf16 [16][512], XOR-swizzled (byte ^= (row&7)<<4): short4 writes,
// conflict-free b128 reads in PV.
__global__ __launch_bounds__(256, 3)
void attn_mfma(const __hip_bfloat16* __restrict__ Qh,
               const __hip_bfloat16* __restrict__ Kh,
               const __hip_bfloat16* __restrict__ Vt,
               const float* __restrict__ bias,
               const float* __restrict__ gaw,
               __hip_bfloat16* __restrict__ A2)
{
    __shared__ __align__(16) short Pb[16 * 512];   // 16 KB
    __shared__ __align__(16) float mpart[16][4];
    __shared__ __align__(16) float spart[16][4];

    // XCD swizzle: each XCD owns 16 consecutive b values (K/V stay in its L2)
    const int flat = blockIdx.y * gridDim.x + blockIdx.x;   // gridDim.x = 32
    const int swz  = (flat & 7) * 512 + (flat >> 3);
    const int b    = swz >> 5;
    const int i0   = (swz & 31) * 16;

    const int tid  = threadIdx.x;
    const int lane = tid & 63;
    const int w    = tid >> 6;
    const int quad = lane >> 4;
    const int l16  = lane & 15;

    // ---- phase 1: S^T tiles = K Q^T (+bias), all loads hoisted ----
    const bf16x8* Qb = reinterpret_cast<const bf16x8*>(
        Qh + ((size_t)b * N_NODE + i0 + l16) * HD + quad * 8);
    const bf16x8 qa0 = Qb[0];
    const bf16x8 qa1 = Qb[4];          // +32 elems

    bf16x8 kf[8][2];
    #pragma unroll
    for (int t = 0; t < 8; ++t) {
        const int jt = w + 4 * t;
        const bf16x8* Kb = reinterpret_cast<const bf16x8*>(
            Kh + ((size_t)b * N_NODE + jt * 16 + l16) * HD + quad * 8);
        kf[t][0] = Kb[0];
        kf[t][1] = Kb[4];
    }
    const float* bp0 = bias + ((size_t)b * N_NODE + i0 + l16) * N_NODE
                     + w * 16 + quad * 4;
    f32x4 breg[8];
    #pragma unroll
    for (int t = 0; t < 8; ++t)
        breg[t] = *reinterpret_cast<const f32x4*>(bp0 + t * 64);

    f32x4 sreg[8];
    float mx = -1e30f;
    #pragma unroll
    for (int t = 0; t < 8; ++t) {
        f32x4 acc = {0.f, 0.f, 0.f, 0.f};
        acc = __builtin_amdgcn_mfma_f32_16x16x32_bf16(kf[t][0], qa0, acc, 0, 0, 0);
        acc = __builtin_amdgcn_mfma_f32_16x16x32_bf16(kf[t][1], qa1, acc, 0, 0, 0);
        acc += breg[t];
        sreg[t] = acc;
        mx = fmaxf(mx, fmaxf(fmaxf(acc[0], acc[1]), fmaxf(acc[2], acc[3])));
    }

    // issue gaw loads now; latency hides under reduce + barrier
    const float* gp0 = gaw + ((size_t)b * N_NODE + i0 + l16) * N_NODE
                     + w * 16 + quad * 4;
    f32x4 greg[8];
    #pragma unroll
    for (int t = 0; t < 8; ++t)
        greg[t] = *reinterpret_cast<const f32x4*>(gp0 + t * 64);

    // row-max: reduce across quads (xor 16,32), then across waves via LDS
    mx = fmaxf(mx, __shfl_xor(mx, 16));
    mx = fmaxf(mx, __shfl_xor(mx, 32));
    if (lane < 16) mpart[l16][w] = mx;
    __syncthreads();

    // ---- phase 2: p = tanh(gaw) * exp(S - m) -> Pb (short4); row-sums ----
    const float4 mp4 = *reinterpret_cast<const float4*>(mpart[l16]);
    const float m = fmaxf(fmaxf(mp4.x, mp4.y), fmaxf(mp4.z, mp4.w));

    // issue V loads now; drained by the __syncthreads below
    const bf16x8* Vb = reinterpret_cast<const bf16x8*>(
        Vt + ((size_t)b * HD + w * 16 + l16) * N_NODE + quad * 8);
    bf16x8 vf[16];
    #pragma unroll
    for (int j32 = 0; j32 < 16; ++j32)
        vf[j32] = Vb[j32 * 4];         // +32 elems per step

    float sum = 0.f;
    #pragma unroll
    for (int t = 0; t < 8; ++t) {
        const int jt = w + 4 * t;
        short4 p4;
        {
            const float e0 = __expf(sreg[t][0] - m);
            const float e1 = __expf(sreg[t][1] - m);
            const float e2 = __expf(sreg[t][2] - m);
            const float e3 = __expf(sreg[t][3] - m);
            sum += (e0 + e1) + (e2 + e3);
            p4.x = f2bs(fast_tanh(greg[t][0]) * e0);
            p4.y = f2bs(fast_tanh(greg[t][1]) * e1);
            p4.z = f2bs(fast_tanh(greg[t][2]) * e2);
            p4.w = f2bs(fast_tanh(greg[t][3]) * e3);
        }
        const int byte = l16 * 1024 + ((jt * 32 + quad * 8) ^ ((l16 & 7) << 4));
        *reinterpret_cast<short4*>(reinterpret_cast<char*>(Pb) + byte) = p4;
    }
    sum += __shfl_xor(sum, 16);
    sum += __shfl_xor(sum, 32);
    if (lane < 16) spart[l16][w] = sum;
    __syncthreads();

    // ---- phase 3: O = (P V) * rrs ----
    {
        f32x4 acc = {0.f, 0.f, 0.f, 0.f};
        #pragma unroll
        for (int j32 = 0; j32 < 16; ++j32) {
            const int byte = l16 * 1024
                           + ((j32 * 64 + quad * 16) ^ ((l16 & 7) << 4));
            const bf16x8 af = *reinterpret_cast<const bf16x8*>(
                reinterpret_cast<const char*>(Pb) + byte);
            acc = __builtin_amdgcn_mfma_f32_16x16x32_bf16(af, vf[j32], acc, 0, 0, 0);
        }
        const int node0 = i0 + quad * 4;
        __hip_bfloat16* op = A2 + (size_t)node0 * (N_GRAPH * EDIM)
                           + (b >> 4) * EDIM + (b & 15) * HD + w * 16 + l16;
        #pragma unroll
        for (int r = 0; r < 4; r++) {
            const float4 sp = *reinterpret_cast<const float4*>(spart[quad * 4 + r]);
            const float rs = 1.f / (sp.x + sp.y + sp.z + sp.w);
            op[(size_t)r * (N_GRAPH * EDIM)] = __float2bfloat16(acc[r] * rs);
        }
    }
}

extern "C" void kernel_launch(void* const* d_in, const int* in_sizes, int n_in,
                              void* d_out, int out_size, void* d_ws, size_t ws_size,
                              hipStream_t stream) {
    const float* query     = (const float*)d_in[0];
    const float* attn_bias = (const float*)d_in[1];
    const float* gaw       = (const float*)d_in[2];
    const float* in_w      = (const float*)d_in[3];
    const float* in_b      = (const float*)d_in[4];
    const float* out_w     = (const float*)d_in[5];
    const float* out_b     = (const float*)d_in[6];
    float* out = (float*)d_out;

    // workspace layout (shorts). Requires ws_size >= 40 MB.
    short* wsp = (short*)d_ws;
    const size_t hsz = (size_t)GH * N_NODE * HD;      // 4 Mi elems
    short* Q   = wsp;
    short* K   = wsp + hsz;
    short* V   = wsp + 2 * hsz;
    short* Vt  = wsp + 3 * hsz;
    short* A2  = V;                       // V dead after transpose
    short* qb  = Vt;                      // qb dead before transpose writes Vt
    short* wbi = wsp + 4 * hsz;           // in_w bf16  (3 Mi)
    short* wbo = wbi + (size_t)3 * EDIM * EDIM;  // out_w bf16 (1 Mi)

    // 0) one-time bf16 conversions
    cvt_bf16<<<dim3(MROWS * EDIM / 2048), 256, 0, stream>>>(query, qb, MROWS * EDIM / 8);
    cvt_bf16<<<dim3(3 * EDIM * EDIM / 2048), 256, 0, stream>>>(in_w, wbi, 3 * EDIM * EDIM / 8);
    cvt_bf16<<<dim3(EDIM * EDIM / 2048), 256, 0, stream>>>(out_w, wbo, EDIM * EDIM / 8);

    // 1) fused QKV projection + head-layout scatter (128x128 tiles)
    gemm_bf16<1, 128><<<dim3(24, 32), 256, 0, stream>>>(
        qb, wbi, in_b, nullptr,
        (__hip_bfloat16*)Q, (__hip_bfloat16*)K, (__hip_bfloat16*)V,
        MROWS, 3 * EDIM, EDIM);

    // 2) V -> Vt (overwrites qb, which is dead)
    transpose_v<<<dim3(8, GH), 256, 0, stream>>>(
        (const __hip_bfloat16*)V, (__hip_bfloat16*)Vt);

    // 3) MFMA attention (16-row blocks, swapped QK^T, register S)
    attn_mfma<<<dim3(N_NODE / 16, GH), 256, 0, stream>>>(
        (const __hip_bfloat16*)Q, (const __hip_bfloat16*)K,
        (const __hip_bfloat16*)Vt, attn_bias, gaw, (__hip_bfloat16*)A2);

    // 4) output projection (128x64 tiles -> 512 blocks, 2/CU)
    gemm_bf16<0, 64><<<dim3(16, 32), 256, 0, stream>>>(
        (const short*)A2, wbo, out_b, out,
        nullptr, nullptr, nullptr, MROWS, EDIM, EDIM);
}

// Round 4
// 411.199 us; speedup vs baseline: 1.2513x; 1.0004x over previous
//
#include <hip/hip_runtime.h>
#include <hip/hip_bf16.h>
#include <cstdint>

#define N_NODE 512
#define N_GRAPH 8
#define EDIM 1024
#define NHEADS 16
#define HD 64
#define GH 128       // n_graph * NHEADS
#define MROWS 4096   // n_node * n_graph

typedef short bf16x8 __attribute__((ext_vector_type(8)));
typedef float f32x4  __attribute__((ext_vector_type(4)));

// liveness pin: forces the value to be materialized here (load issued above,
// waited here) and prevents the compiler sinking the load into later loops.
#define PIN(v) asm volatile("" :: "v"(v))

__device__ __forceinline__ short f2bs(float f) {
    union { __hip_bfloat16 h; short s; } u; u.h = __float2bfloat16(f); return u.s;
}
// tanh(x) = 1 - 2/(exp(2x)+1): v_exp + v_rcp path (~5 instr vs libm ~25)
__device__ __forceinline__ float fast_tanh(float x) {
    const float e = __expf(2.f * x);
    return 1.f - __fdividef(2.f, 1.f + e);
}

// async global->LDS, 16 B/lane. LDS dest = wave-uniform base + lane*16.
__device__ __forceinline__ void direct_lds16(const short* g, short* l) {
    __builtin_amdgcn_global_load_lds(
        (const __attribute__((address_space(1))) unsigned int*)(uintptr_t)g,
        (__attribute__((address_space(3))) unsigned int*)(unsigned)(uintptr_t)l,
        16, 0, 0);
}

// ---------------- fp32 -> bf16 bulk convert (one-time, 8 elems/thread) ------
__global__ __launch_bounds__(256)
void cvt_bf16(const float* __restrict__ in, short* __restrict__ out, int n8)
{
    const int i = blockIdx.x * 256 + threadIdx.x;
    if (i >= n8) return;
    const float4 f0 = *reinterpret_cast<const float4*>(in + (size_t)i * 8);
    const float4 f1 = *reinterpret_cast<const float4*>(in + (size_t)i * 8 + 4);
    bf16x8 h;
    h[0] = f2bs(f0.x); h[1] = f2bs(f0.y); h[2] = f2bs(f0.z); h[3] = f2bs(f0.w);
    h[4] = f2bs(f1.x); h[5] = f2bs(f1.y); h[6] = f2bs(f1.z); h[7] = f2bs(f1.w);
    *reinterpret_cast<bf16x8*>(out + (size_t)i * 8) = h;
}

// ---------------- MFMA GEMM: C = A @ B^T + bias, bf16 inputs ----------------
// A [M,K], B [N,K] row-major bf16. 128xBN tile, BK=32. 3-buffer LDS pipeline:
// per K-step {STAGE next -> vmcnt(counted) -> s_barrier -> ds_read+MFMA}.
// Counted vmcnt never drains the just-issued loads (T3+T4). XCD-swizzled grid.
// MODE 0 (BN=64): C row-major fp32. MODE 1 (BN=128): qkv scatter, q*0.125.
template<int MODE, int BN>
__global__ __launch_bounds__(256)
void gemm_bf16(const short* __restrict__ A, const short* __restrict__ B,
               const float* __restrict__ bias, float* __restrict__ Cout,
               __hip_bfloat16* __restrict__ Cq,
               __hip_bfloat16* __restrict__ Ck,
               __hip_bfloat16* __restrict__ Cv,
               int M, int N, int K)
{
    __shared__ short As[3][128 * 32];
    __shared__ short Bs[3][BN * 32];

    // XCD swizzle: contiguous logical-tile chunk per XCD (both grids % 8 == 0)
    const int nwg  = gridDim.x * gridDim.y;
    const int flat = blockIdx.y * gridDim.x + blockIdx.x;
    const int q8   = nwg >> 3;
    const int swz  = (flat & 7) * q8 + (flat >> 3);
    const int bx   = swz % gridDim.x;
    const int by   = swz / gridDim.x;

    const int tid  = threadIdx.x;
    const int m0   = by * 128;
    const int n0   = bx * BN;
    const int lane = tid & 63;
    const int w    = tid >> 6;
    const int l16  = lane & 15;
    const int quad = lane >> 4;
    const int wm   = w & 1;
    const int wn   = w >> 1;
    const int lrow = lane >> 2;        // 0..15 row within 16-row staging chunk
    const int lcol = (lane & 3) << 3;  // 0/8/16/24 shorts within BK=32

    const short* ga = A + (size_t)(m0 + w * 16 + lrow) * K + lcol;
    const short* gb = B + (size_t)(n0 + w * 16 + lrow) * K + lcol;

    constexpr int NTC = BN / 32;       // col fragments per wave (4 or 2)

    f32x4 acc[4][NTC];
    #pragma unroll
    for (int mt = 0; mt < 4; mt++)
        #pragma unroll
        for (int nt = 0; nt < NTC; nt++)
            acc[mt][nt] = (f32x4){0.f, 0.f, 0.f, 0.f};

    auto STAGE = [&](int kk, int buf) {
        short* lA = &As[buf][w * 512];
        direct_lds16(ga + kk, lA);
        direct_lds16(ga + (size_t)64 * K + kk, lA + 2048);
        short* lB = &Bs[buf][w * 512];
        direct_lds16(gb + kk, lB);
        if constexpr (BN == 128)
            direct_lds16(gb + (size_t)64 * K + kk, lB + 2048);
    };

    const int NT = K >> 5;             // 32 K-steps
    STAGE(0, 0);
    int cur = 0, nxt = 1;
    for (int t = 0; t < NT; ++t) {
        if (t + 1 < NT) {
            STAGE((t + 1) << 5, nxt);
            if constexpr (BN == 128)
                asm volatile("s_waitcnt vmcnt(4)" ::: "memory");
            else
                asm volatile("s_waitcnt vmcnt(3)" ::: "memory");
        } else {
            asm volatile("s_waitcnt vmcnt(0)" ::: "memory");
        }
        __builtin_amdgcn_s_barrier();
        __builtin_amdgcn_sched_barrier(0);

        bf16x8 af[4], bfr[NTC];
        #pragma unroll
        for (int mt = 0; mt < 4; mt++)
            af[mt] = *reinterpret_cast<const bf16x8*>(
                &As[cur][(wm * 64 + mt * 16 + l16) * 32 + quad * 8]);
        #pragma unroll
        for (int nt = 0; nt < NTC; nt++)
            bfr[nt] = *reinterpret_cast<const bf16x8*>(
                &Bs[cur][(wn * (BN / 2) + nt * 16 + l16) * 32 + quad * 8]);
        #pragma unroll
        for (int mt = 0; mt < 4; mt++)
            #pragma unroll
            for (int nt = 0; nt < NTC; nt++)
                acc[mt][nt] = __builtin_amdgcn_mfma_f32_16x16x32_bf16(
                    af[mt], bfr[nt], acc[mt][nt], 0, 0, 0);

        cur = (cur == 2) ? 0 : cur + 1;
        nxt = (nxt == 2) ? 0 : nxt + 1;
    }

    // epilogue: C[m = quad*4+reg (+tiles)][n = l16 (+tiles)]
    #pragma unroll
    for (int nt = 0; nt < NTC; nt++) {
        const int c = n0 + wn * (BN / 2) + nt * 16 + l16;
        const float bv = bias[c];
        #pragma unroll
        for (int mt = 0; mt < 4; mt++) {
            #pragma unroll
            for (int rr = 0; rr < 4; rr++) {
                const int r = m0 + wm * 64 + mt * 16 + quad * 4 + rr;
                const float v = acc[mt][nt][rr] + bv;
                if (MODE == 0) {
                    Cout[(size_t)r * N + c] = v;
                } else {
                    const int qsel = c >> 10;          // 0=q 1=k 2=v
                    const int e = c & 1023;
                    const int head = e >> 6;
                    const int d = e & 63;
                    const int node = r >> 3;
                    const int graph = r & 7;
                    const int b = graph * NHEADS + head;
                    const size_t idx = ((size_t)b * N_NODE + node) * HD + d;
                    if (qsel == 0)      Cq[idx] = __float2bfloat16(v * 0.125f);
                    else if (qsel == 1) Ck[idx] = __float2bfloat16(v);
                    else                Cv[idx] = __float2bfloat16(v);
                }
            }
        }
    }
}

// ---------------- V transpose: [GH][512][64] -> [GH][64][512] ----------------
__global__ __launch_bounds__(256)
void transpose_v(const __hip_bfloat16* __restrict__ V,
                 __hip_bfloat16* __restrict__ Vt)
{
    __shared__ short T[64][80];
    const int b = blockIdx.y;
    const int jt = blockIdx.x;    // 8 tiles of 64 j
    const int t = threadIdx.x;

    #pragma unroll
    for (int it = 0; it < 2; it++) {
        const int idx = t + it * 256;          // 0..511
        const int j_loc = idx >> 3;
        const int ch = idx & 7;
        bf16x8 v = *reinterpret_cast<const bf16x8*>(
            V + ((size_t)b * N_NODE + jt * 64 + j_loc) * HD + ch * 8);
        *reinterpret_cast<bf16x8*>(&T[j_loc][ch * 8]) = v;
    }
    __syncthreads();
    #pragma unroll
    for (int it = 0; it < 2; it++) {
        const int idx = t + it * 256;
        const int d_loc = idx >> 3;
        const int ch = idx & 7;
        bf16x8 o;
        #pragma unroll
        for (int x = 0; x < 8; x++) o[x] = T[ch * 8 + x][d_loc];
        *reinterpret_cast<bf16x8*>(
            Vt + ((size_t)b * HD + d_loc) * N_NODE + jt * 64 + ch * 8) = o;
    }
}

// ---------------- MFMA attention: swapped QK^T, PINNED deep-MLP loads --------
// mfma(K,Q) -> lane (quad,l16) holds S[row = i0+l16][col = jt*16+quad*4+r].
// All 26 phase-1 loads (qa, kf, bias) issued back-to-back then PINned: one
// latency for the batch instead of 26 serial chains (R3's failure: compiler
// sank the arrays at VGPR=60). gaw issued+pinned before the phase-1 barrier;
// V issued at phase-2 top, pinned before the phase-2 barrier.
__global__ __launch_bounds__(256, 3)
void attn_mfma(const __hip_bfloat16* __restrict__ Qh,
               const __hip_bfloat16* __restrict__ Kh,
               const __hip_bfloat16* __restrict__ Vt,
               const float* __restrict__ bias,
               const float* __restrict__ gaw,
               __hip_bfloat16* __restrict__ A2)
{
    __shared__ __align__(16) short Pb[16 * 512];   // 16 KB
    __shared__ __align__(16) float mpart[16][4];
    __shared__ __align__(16) float spart[16][4];

    // XCD swizzle: each XCD owns 16 consecutive b values (K/V stay in its L2)
    const int flat = blockIdx.y * gridDim.x + blockIdx.x;   // gridDim.x = 32
    const int swz  = (flat & 7) * 512 + (flat >> 3);
    const int b    = swz >> 5;
    const int i0   = (swz & 31) * 16;

    const int tid  = threadIdx.x;
    const int lane = tid & 63;
    const int w    = tid >> 6;
    const int quad = lane >> 4;
    const int l16  = lane & 15;

    // ---- phase 1: issue qa + 16 K + 8 bias loads, pin, then MFMA ----
    const bf16x8* Qb = reinterpret_cast<const bf16x8*>(
        Qh + ((size_t)b * N_NODE + i0 + l16) * HD + quad * 8);
    const bf16x8 qa0 = Qb[0];
    const bf16x8 qa1 = Qb[4];          // +32 elems

    bf16x8 kf[8][2];
    #pragma unroll
    for (int t = 0; t < 8; ++t) {
        const int jt = w + 4 * t;
        const bf16x8* Kb = reinterpret_cast<const bf16x8*>(
            Kh + ((size_t)b * N_NODE + jt * 16 + l16) * HD + quad * 8);
        kf[t][0] = Kb[0];
        kf[t][1] = Kb[4];
    }
    const float* bp0 = bias + ((size_t)b * N_NODE + i0 + l16) * N_NODE
                     + w * 16 + quad * 4;
    f32x4 breg[8];
    #pragma unroll
    for (int t = 0; t < 8; ++t)
        breg[t] = *reinterpret_cast<const f32x4*>(bp0 + t * 64);

    PIN(qa0); PIN(qa1);
    #pragma unroll
    for (int t = 0; t < 8; ++t) { PIN(kf[t][0]); PIN(kf[t][1]); }
    #pragma unroll
    for (int t = 0; t < 8; ++t) PIN(breg[t]);

    f32x4 sreg[8];
    float mx = -1e30f;
    #pragma unroll
    for (int t = 0; t < 8; ++t) {
        f32x4 acc = {0.f, 0.f, 0.f, 0.f};
        acc = __builtin_amdgcn_mfma_f32_16x16x32_bf16(kf[t][0], qa0, acc, 0, 0, 0);
        acc = __builtin_amdgcn_mfma_f32_16x16x32_bf16(kf[t][1], qa1, acc, 0, 0, 0);
        acc += breg[t];
        sreg[t] = acc;
        mx = fmaxf(mx, fmaxf(fmaxf(acc[0], acc[1]), fmaxf(acc[2], acc[3])));
    }

    // issue gaw loads now; pinned before the barrier so the wait overlaps
    // the reduce + barrier of every wave
    const float* gp0 = gaw + ((size_t)b * N_NODE + i0 + l16) * N_NODE
                     + w * 16 + quad * 4;
    f32x4 greg[8];
    #pragma unroll
    for (int t = 0; t < 8; ++t)
        greg[t] = *reinterpret_cast<const f32x4*>(gp0 + t * 64);

    // row-max: reduce across quads (xor 16,32), then across waves via LDS
    mx = fmaxf(mx, __shfl_xor(mx, 16));
    mx = fmaxf(mx, __shfl_xor(mx, 32));
    if (lane < 16) mpart[l16][w] = mx;
    #pragma unroll
    for (int t = 0; t < 8; ++t) PIN(greg[t]);
    __syncthreads();

    // ---- phase 2: p = tanh(gaw) * exp(S - m) -> Pb (short4); row-sums ----
    const float4 mp4 = *reinterpret_cast<const float4*>(mpart[l16]);
    const float m = fmaxf(fmaxf(mp4.x, mp4.y), fmaxf(mp4.z, mp4.w));

    // issue V loads now; pinned before the phase-2 barrier (waits overlap
    // the exp/tanh VALU work below)
    const bf16x8* Vb = reinterpret_cast<const bf16x8*>(
        Vt + ((size_t)b * HD + w * 16 + l16) * N_NODE + quad * 8);
    bf16x8 vf[16];
    #pragma unroll
    for (int j32 = 0; j32 < 16; ++j32)
        vf[j32] = Vb[j32 * 4];         // +32 elems per step

    float sum = 0.f;
    #pragma unroll
    for (int t = 0; t < 8; ++t) {
        const int jt = w + 4 * t;
        short4 p4;
        {
            const float e0 = __expf(sreg[t][0] - m);
            const float e1 = __expf(sreg[t][1] - m);
            const float e2 = __expf(sreg[t][2] - m);
            const float e3 = __expf(sreg[t][3] - m);
            sum += (e0 + e1) + (e2 + e3);
            p4.x = f2bs(fast_tanh(greg[t][0]) * e0);
            p4.y = f2bs(fast_tanh(greg[t][1]) * e1);
            p4.z = f2bs(fast_tanh(greg[t][2]) * e2);
            p4.w = f2bs(fast_tanh(greg[t][3]) * e3);
        }
        const int byte = l16 * 1024 + ((jt * 32 + quad * 8) ^ ((l16 & 7) << 4));
        *reinterpret_cast<short4*>(reinterpret_cast<char*>(Pb) + byte) = p4;
    }
    sum += __shfl_xor(sum, 16);
    sum += __shfl_xor(sum, 32);
    if (lane < 16) spart[l16][w] = sum;
    #pragma unroll
    for (int j32 = 0; j32 < 16; ++j32) PIN(vf[j32]);
    __syncthreads();

    // ---- phase 3: O = (P V) * rrs ----
    {
        f32x4 acc = {0.f, 0.f, 0.f, 0.f};
        #pragma unroll
        for (int j32 = 0; j32 < 16; ++j32) {
            const int byte = l16 * 1024
                           + ((j32 * 64 + quad * 16) ^ ((l16 & 7) << 4));
            const bf16x8 af = *reinterpret_cast<const bf16x8*>(
                reinterpret_cast<const char*>(Pb) + byte);
            acc = __builtin_amdgcn_mfma_f32_16x16x32_bf16(af, vf[j32], acc, 0, 0, 0);
        }
        const int node0 = i0 + quad * 4;
        __hip_bfloat16* op = A2 + (size_t)node0 * (N_GRAPH * EDIM)
                           + (b >> 4) * EDIM + (b & 15) * HD + w * 16 + l16;
        #pragma unroll
        for (int r = 0; r < 4; r++) {
            const float4 sp = *reinterpret_cast<const float4*>(spart[quad * 4 + r]);
            const float rs = 1.f / (sp.x + sp.y + sp.z + sp.w);
            op[(size_t)r * (N_GRAPH * EDIM)] = __float2bfloat16(acc[r] * rs);
        }
    }
}

extern "C" void kernel_launch(void* const* d_in, const int* in_sizes, int n_in,
                              void* d_out, int out_size, void* d_ws, size_t ws_size,
                              hipStream_t stream) {
    const float* query     = (const float*)d_in[0];
    const float* attn_bias = (const float*)d_in[1];
    const float* gaw       = (const float*)d_in[2];
    const float* in_w      = (const float*)d_in[3];
    const float* in_b      = (const float*)d_in[4];
    const float* out_w     = (const float*)d_in[5];
    const float* out_b     = (const float*)d_in[6];
    float* out = (float*)d_out;

    // workspace layout (shorts). Requires ws_size >= 40 MB.
    short* wsp = (short*)d_ws;
    const size_t hsz = (size_t)GH * N_NODE * HD;      // 4 Mi elems
    short* Q   = wsp;
    short* K   = wsp + hsz;
    short* V   = wsp + 2 * hsz;
    short* Vt  = wsp + 3 * hsz;
    short* A2  = V;                       // V dead after transpose
    short* qb  = Vt;                      // qb dead before transpose writes Vt
    short* wbi = wsp + 4 * hsz;           // in_w bf16  (3 Mi)
    short* wbo = wbi + (size_t)3 * EDIM * EDIM;  // out_w bf16 (1 Mi)

    // 0) one-time bf16 conversions
    cvt_bf16<<<dim3(MROWS * EDIM / 2048), 256, 0, stream>>>(query, qb, MROWS * EDIM / 8);
    cvt_bf16<<<dim3(3 * EDIM * EDIM / 2048), 256, 0, stream>>>(in_w, wbi, 3 * EDIM * EDIM / 8);
    cvt_bf16<<<dim3(EDIM * EDIM / 2048), 256, 0, stream>>>(out_w, wbo, EDIM * EDIM / 8);

    // 1) fused QKV projection + head-layout scatter (128x128 tiles)
    gemm_bf16<1, 128><<<dim3(24, 32), 256, 0, stream>>>(
        qb, wbi, in_b, nullptr,
        (__hip_bfloat16*)Q, (__hip_bfloat16*)K, (__hip_bfloat16*)V,
        MROWS, 3 * EDIM, EDIM);

    // 2) V -> Vt (overwrites qb, which is dead)
    transpose_v<<<dim3(8, GH), 256, 0, stream>>>(
        (const __hip_bfloat16*)V, (__hip_bfloat16*)Vt);

    // 3) MFMA attention (16-row blocks, swapped QK^T, pinned deep-MLP)
    attn_mfma<<<dim3(N_NODE / 16, GH), 256, 0, stream>>>(
        (const __hip_bfloat16*)Q, (const __hip_bfloat16*)K,
        (const __hip_bfloat16*)Vt, attn_bias, gaw, (__hip_bfloat16*)A2);

    // 4) output projection (128x64 tiles -> 512 blocks, 2/CU)
    gemm_bf16<0, 64><<<dim3(16, 32), 256, 0, stream>>>(
        (const short*)A2, wbo, out_b, out,
        nullptr, nullptr, nullptr, MROWS, EDIM, EDIM);
}